// Round 2
// baseline (2503.575 us; speedup 1.0000x reference)
//
#include <hip/hip_runtime.h>

// ---------- sizes ----------
#define BB_   2
#define LL_   2048
#define DD_   2048
#define HV_   32
#define HK_   16
#define MM_   (BB_*LL_)          // 4096 rows
#define KEYD_ 2048
#define VALD_ 4096
#define CONVD_ 8192

typedef _Float16 half8v  __attribute__((ext_vector_type(8)));
typedef _Float16 half4v  __attribute__((ext_vector_type(4)));
typedef float    f32x4   __attribute__((ext_vector_type(4)));
typedef unsigned int uint4v __attribute__((ext_vector_type(4)));

// ===================== convert f32 -> f16 (vectorized) =====================
__global__ __launch_bounds__(256) void k_convert(const float* __restrict__ src,
                                                 _Float16* __restrict__ dst, int n4) {
    int i = blockIdx.x * 256 + threadIdx.x;
    if (i < n4) {
        f32x4 v = *(const f32x4*)(src + (size_t)i * 4);
        half4v h;
        h.x = (_Float16)v.x; h.y = (_Float16)v.y; h.z = (_Float16)v.z; h.w = (_Float16)v.w;
        *(half4v*)(dst + (size_t)i * 4) = h;
    }
}

// ============ convert + transpose: src f32 [K][N] -> dst f16 [N][K] ============
__global__ __launch_bounds__(256) void k_transpose(const float* __restrict__ src,
                                                   _Float16* __restrict__ dst, int K, int N) {
    __shared__ float tile[32][33];
    int tx = threadIdx.x & 31, ty = threadIdx.x >> 5;      // 32 x 8
    int n0 = blockIdx.x * 32, k0 = blockIdx.y * 32;
#pragma unroll
    for (int j = 0; j < 4; j++)
        tile[ty + j * 8][tx] = src[(size_t)(k0 + ty + j * 8) * N + n0 + tx];
    __syncthreads();
#pragma unroll
    for (int j = 0; j < 4; j++)
        dst[(size_t)(n0 + ty + j * 8) * K + k0 + tx] = (_Float16)tile[tx][ty + j * 8];
}

// ===================== GEMM: C[M][N] = A[M][K] * Bt[N][K]^T =====================
// f16 inputs, fp32 accumulate via v_mfma_f32_16x16x32_f16. 128x128 tile, BK=32.
template <bool OUT_F16>
__global__ __launch_bounds__(256) void k_gemm(const _Float16* __restrict__ A,
                                              const _Float16* __restrict__ Bt,
                                              void* __restrict__ Cv,
                                              int Mdim, int Ndim, int Kdim) {
    __shared__ __align__(16) _Float16 As[128 * 40];   // +8 pad
    __shared__ __align__(16) _Float16 Bs[128 * 40];
    const int m0 = blockIdx.y * 128, n0 = blockIdx.x * 128;
    const int t = threadIdx.x;
    const int wave = t >> 6, lane = t & 63;
    const int wm = wave & 1, wn = wave >> 1;           // 2x2 waves of 64x64
    const int r16 = lane & 15, quad = lane >> 4;

    f32x4 acc[4][4];
#pragma unroll
    for (int i = 0; i < 4; i++)
#pragma unroll
        for (int j = 0; j < 4; j++) acc[i][j] = (f32x4){0.f, 0.f, 0.f, 0.f};

    for (int k0 = 0; k0 < Kdim; k0 += 32) {
#pragma unroll
        for (int c = t; c < 512; c += 256) {           // 512 x 16B per tile
            int row = c >> 2, q4 = c & 3;
            *(uint4v*)(&As[row * 40 + q4 * 8]) =
                *(const uint4v*)(&A[(size_t)(m0 + row) * Kdim + k0 + q4 * 8]);
            *(uint4v*)(&Bs[row * 40 + q4 * 8]) =
                *(const uint4v*)(&Bt[(size_t)(n0 + row) * Kdim + k0 + q4 * 8]);
        }
        __syncthreads();
        half8v af[4], bf[4];
#pragma unroll
        for (int i = 0; i < 4; i++) {
            af[i] = *(const half8v*)(&As[(wm * 64 + i * 16 + r16) * 40 + quad * 8]);
            bf[i] = *(const half8v*)(&Bs[(wn * 64 + i * 16 + r16) * 40 + quad * 8]);
        }
#pragma unroll
        for (int i = 0; i < 4; i++)
#pragma unroll
            for (int j = 0; j < 4; j++)
                acc[i][j] = __builtin_amdgcn_mfma_f32_16x16x32_f16(af[i], bf[j], acc[i][j], 0, 0, 0);
        __syncthreads();
    }
    // epilogue: D row = quad*4+r, col = r16
#pragma unroll
    for (int i = 0; i < 4; i++)
#pragma unroll
        for (int j = 0; j < 4; j++)
#pragma unroll
            for (int r = 0; r < 4; r++) {
                int rg = m0 + wm * 64 + i * 16 + quad * 4 + r;
                int cg = n0 + wn * 64 + j * 16 + r16;
                float v = acc[i][j][r];
                if (OUT_F16) ((_Float16*)Cv)[(size_t)rg * Ndim + cg] = (_Float16)v;
                else         ((float*)Cv)[(size_t)rg * Ndim + cg] = v;
            }
}

// ========== b/a projections (N=32 each) + beta/g activation, one row/block ==========
__global__ __launch_bounds__(256) void k_ba(const float* __restrict__ hidden,
                                            const float* __restrict__ Wb,
                                            const float* __restrict__ Wa,
                                            const float* __restrict__ dt_bias,
                                            const float* __restrict__ A_log,
                                            float* __restrict__ gout,
                                            float* __restrict__ betaout) {
    int row = blockIdx.x;
    __shared__ float xs[2048];
    __shared__ float part[4][64];
    int t = threadIdx.x;
    for (int c = t; c < 512; c += 256)
        *(f32x4*)&xs[c * 4] = *(const f32x4*)&hidden[(size_t)row * 2048 + c * 4];
    __syncthreads();
    int col = t & 63, kq = t >> 6;
    const float* W = (col < 32) ? Wb : Wa;
    int cc = col & 31;
    float p = 0.f;
#pragma unroll 4
    for (int k = kq * 512; k < kq * 512 + 512; k++)
        p += xs[k] * W[(size_t)k * 32 + cc];
    part[kq][col] = p;
    __syncthreads();
    if (t < 64) {
        float v = part[0][t] + part[1][t] + part[2][t] + part[3][t];
        if (t < 32) {
            betaout[(size_t)row * 32 + t] = 1.f / (1.f + __expf(-v));
        } else {
            int hh = t - 32;
            float x = v + dt_bias[hh];
            float sp = (x > 20.f) ? x : log1pf(__expf(x));
            gout[(size_t)row * 32 + hh] = -__expf(A_log[hh]) * sp;
        }
    }
}

// ===== causal depthwise conv (K=4) + SiLU + split + l2norm(q,k), one row/block =====
// outputs f16 q,k (normalized) and f16 v
__global__ __launch_bounds__(256) void k_conv(const _Float16* __restrict__ mixed,
                                              const float* __restrict__ conv_w,
                                              _Float16* __restrict__ qout,
                                              _Float16* __restrict__ kout,
                                              _Float16* __restrict__ vout) {
    int row = blockIdx.x;
    int l = row & (LL_ - 1);
    __shared__ float yv[CONVD_];
    __shared__ float red[256];
    __shared__ float rinvs[32];
    int t = threadIdx.x;
    for (int c = t; c < CONVD_; c += 256) {
        float acc = 0.f;
#pragma unroll
        for (int j = 0; j < 4; j++) {
            int sl = l - 3 + j;          // guard uses in-sequence index (per-batch causal pad)
            if (sl >= 0) acc += (float)mixed[(size_t)(row - 3 + j) * CONVD_ + c] * conv_w[c * 4 + j];
        }
        yv[c] = acc / (1.f + __expf(-acc));            // SiLU
    }
    __syncthreads();
    // sum of squares per head segment (16 q heads, 16 k heads), 8 threads/segment
    int seg = t >> 3, j8 = t & 7;
    int base = (seg < 16) ? seg * 128 : 2048 + (seg - 16) * 128;
    float ss = 0.f;
#pragma unroll
    for (int i = 0; i < 16; i++) { float vv = yv[base + j8 * 16 + i]; ss += vv * vv; }
    red[t] = ss;
    __syncthreads();
    if (t < 32) {
        float tot = 0.f;
#pragma unroll
        for (int jj = 0; jj < 8; jj++) tot += red[t * 8 + jj];
        rinvs[t] = rsqrtf(tot + 1e-6f);                // l2norm: sum + eps
    }
    __syncthreads();
    for (int c = t; c < CONVD_; c += 256) {
        float y = yv[c];
        if (c < 2048) {
            qout[(size_t)row * 2048 + c] = (_Float16)(y * rinvs[c >> 7] * 0.08838834764831843f); // DK^-0.5
        } else if (c < 4096) {
            int c2 = c - 2048;
            kout[(size_t)row * 2048 + c2] = (_Float16)(y * rinvs[16 + (c2 >> 7)]);
        } else {
            vout[(size_t)row * 4096 + (c - 4096)] = y;   // implicit f32->f16
        }
    }
}

// ===================== gated delta-rule scan =====================
// Recurrence is independent per dv column. One wave per (b, h, 16-dv tile):
// lane = (dv = l&15, dk group = l>>4 of 32). State 32 f32/lane in VGPRs.
#define LOADSTEP(T, KA, QA, VA, GA, BA)                                   \
    do {                                                                  \
        const _Float16* kp_ = kb_ + (size_t)(T) * 2048;                   \
        const _Float16* qp_ = qb_ + (size_t)(T) * 2048;                   \
        _Pragma("unroll")                                                 \
        for (int i8 = 0; i8 < 4; i8++) {                                  \
            half8v kv8_ = *(const half8v*)(kp_ + i8 * 8);                 \
            half8v qv8_ = *(const half8v*)(qp_ + i8 * 8);                 \
            _Pragma("unroll")                                             \
            for (int jj = 0; jj < 8; jj++) {                              \
                KA[i8 * 8 + jj] = (float)kv8_[jj];                        \
                QA[i8 * 8 + jj] = (float)qv8_[jj];                        \
            }                                                             \
        }                                                                 \
        VA = (float)vb_[(size_t)(T) * 4096];                              \
        GA = gb_[(size_t)(T) * 32];                                       \
        BA = bb2_[(size_t)(T) * 32];                                      \
    } while (0)

// 4-way partial sums: cuts the serial FMA chain 32 -> 8 on the critical path
#define COMPUTE(T, KA, QA, VA, GA, BA)                                    \
    do {                                                                  \
        float eg_ = __expf(GA);                                           \
        _Pragma("unroll")                                                 \
        for (int ii = 0; ii < 32; ii++) s[ii] *= eg_;                     \
        float p0_ = 0.f, p1_ = 0.f, p2_ = 0.f, p3_ = 0.f;                 \
        _Pragma("unroll")                                                 \
        for (int ii = 0; ii < 8; ii++) {                                  \
            p0_ += KA[ii] * s[ii];        p1_ += KA[8 + ii] * s[8 + ii];  \
            p2_ += KA[16 + ii] * s[16 + ii]; p3_ += KA[24 + ii] * s[24 + ii]; } \
        float kvp_ = (p0_ + p1_) + (p2_ + p3_);                           \
        kvp_ += __shfl_xor(kvp_, 16);                                     \
        kvp_ += __shfl_xor(kvp_, 32);                                     \
        float dlt_ = (VA - kvp_) * BA;                                    \
        _Pragma("unroll")                                                 \
        for (int ii = 0; ii < 32; ii++) s[ii] += KA[ii] * dlt_;           \
        float q0_ = 0.f, q1_ = 0.f, q2_ = 0.f, q3_ = 0.f;                 \
        _Pragma("unroll")                                                 \
        for (int ii = 0; ii < 8; ii++) {                                  \
            q0_ += QA[ii] * s[ii];        q1_ += QA[8 + ii] * s[8 + ii];  \
            q2_ += QA[16 + ii] * s[16 + ii]; q3_ += QA[24 + ii] * s[24 + ii]; } \
        float op_ = (q0_ + q1_) + (q2_ + q3_);                            \
        op_ += __shfl_xor(op_, 16);                                       \
        op_ += __shfl_xor(op_, 32);                                       \
        if (l < 16) ob_[(size_t)(T) * 4096] = (_Float16)op_;              \
    } while (0)

__global__ __launch_bounds__(64) void k_scan(const _Float16* __restrict__ q,
                                             const _Float16* __restrict__ k,
                                             const _Float16* __restrict__ v,
                                             const float* __restrict__ g,
                                             const float* __restrict__ beta,
                                             _Float16* __restrict__ o) {
    int bid = blockIdx.x;          // 512 = 2 * 32 * 8
    int b   = bid >> 8;
    int rem = bid & 255;
    int h   = rem >> 3;
    int dt  = rem & 7;
    int l   = threadIdx.x;
    int dv  = dt * 16 + (l & 15);
    int dk0 = (l >> 4) * 32;
    int hk  = h >> 1;              // GQA repeat_interleave

    float s[32];
#pragma unroll
    for (int i = 0; i < 32; i++) s[i] = 0.f;

    const _Float16* kb_  = k + ((size_t)(b * LL_) * 16 + hk) * 128 + dk0;
    const _Float16* qb_  = q + ((size_t)(b * LL_) * 16 + hk) * 128 + dk0;
    const _Float16* vb_  = v + ((size_t)(b * LL_) * 32 + h) * 128 + dv;
    const float*    gb_  = g + (size_t)(b * LL_) * 32 + h;
    const float*    bb2_ = beta + (size_t)(b * LL_) * 32 + h;
    _Float16*       ob_  = o + ((size_t)(b * LL_) * 32 + h) * 128 + dv;

    float ka[32], qa[32], kc[32], qc[32];
    float va, ga, ba, vc, gc, bc;
    LOADSTEP(0, ka, qa, va, ga, ba);
    for (int t = 0; t < LL_; t += 2) {
        LOADSTEP(t + 1, kc, qc, vc, gc, bc);
        COMPUTE(t, ka, qa, va, ga, ba);
        if (t + 2 < LL_) LOADSTEP(t + 2, ka, qa, va, ga, ba);
        COMPUTE(t + 1, kc, qc, vc, gc, bc);
    }
}

// ===================== gated RMSNorm, one row/block, reads f16 o, writes f16 =====================
__global__ __launch_bounds__(256) void k_rmsnorm(const _Float16* __restrict__ o,
                                                 const _Float16* __restrict__ z,
                                                 const float* __restrict__ norm_w,
                                                 _Float16* __restrict__ gn) {
    int row = blockIdx.x;
    __shared__ float gv[4096];
    __shared__ float red[256];
    __shared__ float rinv[32];
    int t = threadIdx.x;
    int h = t >> 3, j = t & 7;
    size_t base = (size_t)row * 4096 + h * 128 + j * 16;
    float ss = 0.f;
#pragma unroll
    for (int i = 0; i < 16; i++) {
        float ov = (float)o[base + i];
        float zv = (float)z[base + i];
        float gg = ov * zv / (1.f + __expf(-zv));     // core * silu(z)
        gv[h * 128 + j * 16 + i] = gg;
        ss += gg * gg;
    }
    red[t] = ss;
    __syncthreads();
    if (t < 32) {
        float tot = 0.f;
#pragma unroll
        for (int jj = 0; jj < 8; jj++) tot += red[t * 8 + jj];
        rinv[t] = rsqrtf(tot * (1.f / 128.f) + 1e-6f);  // mean + EPS
    }
    __syncthreads();
#pragma unroll
    for (int i = 0; i < 16; i++) {
        int idx = h * 128 + j * 16 + i;
        gn[(size_t)row * 4096 + idx] = (_Float16)(gv[idx] * rinv[h] * norm_w[idx & 127]);
    }
}

// ===================== launch =====================
// Workspace layout (145 MB span, heavy aliasing; all aliases are stream-ordered
// write-after-last-read):
//   [  0, 16) XH f16 (r: GEMM1,GEMM2)          -> GN f16 [0,32) (w: rmsnorm, r: GEMM3)
//   [ 16, 48) WQKVT f16 (r: GEMM1)             -> QB [16,32) + KB [32,48) f16 (w: conv, r: scan)
//   [ 48,112) MIXED f16 (w: GEMM1, r: conv)    -> OB f16 [48,80) (w: scan, r: rmsnorm)
//                                              -> WZT f16 [80,96) (w: transpose, r: GEMM2)
//   [ 96,128) ZH f16 (w: GEMM2 after scan, r: rmsnorm)   [overlaps dead MIXED tail + dead VB head]
//   [112,144) VB f16 (w: conv, r: scan)        -> WOUTT f16 [128,144) (w: transpose, r: GEMM3)
//   [144,145) GB + BBUF f32 (w: k_ba, r: scan)
extern "C" void kernel_launch(void* const* d_in, const int* in_sizes, int n_in,
                              void* d_out, int out_size, void* d_ws, size_t ws_size,
                              hipStream_t stream) {
    const float* hidden  = (const float*)d_in[0];
    const float* W_qkv   = (const float*)d_in[1];
    const float* W_z     = (const float*)d_in[2];
    const float* W_b     = (const float*)d_in[3];
    const float* W_a     = (const float*)d_in[4];
    const float* conv_w  = (const float*)d_in[5];
    const float* dt_bias = (const float*)d_in[6];
    const float* A_log   = (const float*)d_in[7];
    const float* norm_w  = (const float*)d_in[8];
    const float* W_out   = (const float*)d_in[9];
    float* out = (float*)d_out;

    const size_t MB = 1ull << 20;
    char* ws = (char*)d_ws;

    // diagnostic guard: if ws is too small, emit zeros (absmax will be exactly
    // max|ref| = 1.84375 -> tells us ws_size was the problem, without faulting)
    if (ws_size < 146 * MB) {
        hipMemsetAsync(d_out, 0, (size_t)out_size * sizeof(float), stream);
        return;
    }

    _Float16* XH    = (_Float16*)(ws + 0 * MB);      // 16MB  [4096][2048]
    _Float16* WQKVT = (_Float16*)(ws + 16 * MB);     // 32MB  [8192][2048]
    _Float16* MIXED = (_Float16*)(ws + 48 * MB);     // 64MB  [4096][8192]
    _Float16* QB    = (_Float16*)(ws + 16 * MB);     // 16MB  [4096][2048]
    _Float16* KB    = (_Float16*)(ws + 32 * MB);     // 16MB  [4096][2048]
    _Float16* VB    = (_Float16*)(ws + 112 * MB);    // 32MB  [4096][4096]
    _Float16* OB    = (_Float16*)(ws + 48 * MB);     // 32MB  [4096][4096]
    _Float16* WZT   = (_Float16*)(ws + 80 * MB);     // 16MB  [4096][2048]
    _Float16* ZH    = (_Float16*)(ws + 96 * MB);     // 32MB  [4096][4096]
    _Float16* GN    = (_Float16*)(ws + 0 * MB);      // 32MB  [4096][4096]
    _Float16* WOUTT = (_Float16*)(ws + 128 * MB);    // 16MB  [2048][4096]
    float*    GB    = (float*)(ws + 144 * MB);       // 0.5MB [4096][32]
    float*    BBUF  = (float*)(ws + 144 * MB + 512 * 1024);

    // 1. hidden -> f16
    k_convert<<<(MM_ * DD_ / 4 + 255) / 256, 256, 0, stream>>>(hidden, XH, MM_ * DD_ / 4);
    // 2. W_qkv [K][N] -> [N][K] f16
    k_transpose<<<dim3(CONVD_ / 32, DD_ / 32), 256, 0, stream>>>(W_qkv, WQKVT, DD_, CONVD_);
    // 3. GEMM1: MIXED = XH @ WQKVT^T
    k_gemm<true><<<dim3(CONVD_ / 128, MM_ / 128), 256, 0, stream>>>(XH, WQKVT, MIXED, MM_, CONVD_, DD_);
    // 4. b/a projections + activations
    k_ba<<<MM_, 256, 0, stream>>>(hidden, W_b, W_a, dt_bias, A_log, GB, BBUF);
    // 5. conv + silu + split + l2norm  (frees WQKVT region for QB/KB)
    k_conv<<<MM_, 256, 0, stream>>>(MIXED, conv_w, QB, KB, VB);
    // 6. scan (frees MIXED region; writes OB)
    k_scan<<<BB_ * HV_ * 8, 64, 0, stream>>>(QB, KB, VB, GB, BBUF, OB);
    // 7. W_z transpose into dead MIXED region
    k_transpose<<<dim3(VALD_ / 32, DD_ / 32), 256, 0, stream>>>(W_z, WZT, DD_, VALD_);
    // 8. GEMM2: ZH = XH @ WZT^T (after scan: VB head is dead)
    k_gemm<true><<<dim3(VALD_ / 128, MM_ / 128), 256, 0, stream>>>(XH, WZT, ZH, MM_, VALD_, DD_);
    // 9. gated RMSNorm -> GN f16 (frees XH/QB region)
    k_rmsnorm<<<MM_, 256, 0, stream>>>(OB, ZH, norm_w, GN);
    // 10. W_out transpose into dead VB tail
    k_transpose<<<dim3(DD_ / 32, VALD_ / 32), 256, 0, stream>>>(W_out, WOUTT, VALD_, DD_);
    // 11. GEMM3: out = GN @ WOUTT^T -> f32 d_out
    k_gemm<false><<<dim3(DD_ / 128, MM_ / 128), 256, 0, stream>>>(GN, WOUTT, out, MM_, DD_, VALD_);
}

// Round 3
// 2118.050 us; speedup vs baseline: 1.1820x; 1.1820x over previous
//
#include <hip/hip_runtime.h>

// ---------- sizes ----------
#define BB_   2
#define LL_   2048
#define DD_   2048
#define HV_   32
#define HK_   16
#define MM_   (BB_*LL_)          // 4096 rows
#define KEYD_ 2048
#define VALD_ 4096
#define CONVD_ 8192

typedef _Float16 half8v  __attribute__((ext_vector_type(8)));
typedef _Float16 half4v  __attribute__((ext_vector_type(4)));
typedef float    f32x4   __attribute__((ext_vector_type(4)));
typedef unsigned int uint4v __attribute__((ext_vector_type(4)));

// async global->LDS DMA, 16B/lane: LDS dest = wave-uniform base + lane*16
typedef __attribute__((address_space(3))) unsigned int  u32_lds;
typedef __attribute__((address_space(1))) const unsigned int u32_glb;
__device__ __forceinline__ void async16(const _Float16* g, _Float16* l) {
    __builtin_amdgcn_global_load_lds((u32_glb*)g, (u32_lds*)l, 16, 0, 0);
}

// ===================== convert f32 -> f16 (vectorized) =====================
__global__ __launch_bounds__(256) void k_convert(const float* __restrict__ src,
                                                 _Float16* __restrict__ dst, int n4) {
    int i = blockIdx.x * 256 + threadIdx.x;
    if (i < n4) {
        f32x4 v = *(const f32x4*)(src + (size_t)i * 4);
        half4v h;
        h.x = (_Float16)v.x; h.y = (_Float16)v.y; h.z = (_Float16)v.z; h.w = (_Float16)v.w;
        *(half4v*)(dst + (size_t)i * 4) = h;
    }
}

// ============ convert + transpose: src f32 [K][N] -> dst f16 [N][K] ============
__global__ __launch_bounds__(256) void k_transpose(const float* __restrict__ src,
                                                   _Float16* __restrict__ dst, int K, int N) {
    __shared__ float tile[32][33];
    int tx = threadIdx.x & 31, ty = threadIdx.x >> 5;      // 32 x 8
    int n0 = blockIdx.x * 32, k0 = blockIdx.y * 32;
#pragma unroll
    for (int j = 0; j < 4; j++)
        tile[ty + j * 8][tx] = src[(size_t)(k0 + ty + j * 8) * N + n0 + tx];
    __syncthreads();
#pragma unroll
    for (int j = 0; j < 4; j++)
        dst[(size_t)(n0 + ty + j * 8) * K + k0 + tx] = (_Float16)tile[tx][ty + j * 8];
}

// ===================== GEMM: C[M][N] = A[M][K] * Bt[N][K]^T =====================
// f16 inputs, fp32 accumulate, 128x128 tile, BK=32, global_load_lds staging (m97-style).
// No LDS pad (DMA requires contiguous lane order); bank conflicts on ds_read accepted.
template <bool OUT_F16>
__global__ __launch_bounds__(256) void k_gemm(const _Float16* __restrict__ A,
                                              const _Float16* __restrict__ Bt,
                                              void* __restrict__ Cv,
                                              int Mdim, int Ndim, int Kdim) {
    __shared__ __align__(16) _Float16 As[128 * 32];   // 8KB
    __shared__ __align__(16) _Float16 Bs[128 * 32];   // 8KB
    const int m0 = blockIdx.y * 128, n0 = blockIdx.x * 128;
    const int t = threadIdx.x;
    const int wave = t >> 6, lane = t & 63;
    const int wm = wave & 1, wn = wave >> 1;           // 2x2 waves of 64x64
    const int r16 = lane & 15, quad = lane >> 4;

    // staging: chunk ci (16B) -> row = ci>>2, col-chunk = ci&3. 2 calls/wave/matrix.
    const int ci0 = wave * 64 + lane;          // [0,256)
    const int ci1 = 256 + ci0;                 // [256,512)
    const _Float16* gA0 = A  + (size_t)(m0 + (ci0 >> 2)) * Kdim + (ci0 & 3) * 8;
    const _Float16* gA1 = A  + (size_t)(m0 + (ci1 >> 2)) * Kdim + (ci1 & 3) * 8;
    const _Float16* gB0 = Bt + (size_t)(n0 + (ci0 >> 2)) * Kdim + (ci0 & 3) * 8;
    const _Float16* gB1 = Bt + (size_t)(n0 + (ci1 >> 2)) * Kdim + (ci1 & 3) * 8;
    _Float16* lA0 = As + wave * 512;           // ci0 base (f16 units)
    _Float16* lA1 = As + 2048 + wave * 512;    // ci1 base
    _Float16* lB0 = Bs + wave * 512;
    _Float16* lB1 = Bs + 2048 + wave * 512;

    f32x4 acc[4][4];
#pragma unroll
    for (int i = 0; i < 4; i++)
#pragma unroll
        for (int j = 0; j < 4; j++) acc[i][j] = (f32x4){0.f, 0.f, 0.f, 0.f};

    for (int k0 = 0; k0 < Kdim; k0 += 32) {
        async16(gA0 + k0, lA0);
        async16(gA1 + k0, lA1);
        async16(gB0 + k0, lB0);
        async16(gB1 + k0, lB1);
        __syncthreads();
        half8v af[4], bf[4];
#pragma unroll
        for (int i = 0; i < 4; i++) {
            af[i] = *(const half8v*)(&As[(wm * 64 + i * 16 + r16) * 32 + quad * 8]);
            bf[i] = *(const half8v*)(&Bs[(wn * 64 + i * 16 + r16) * 32 + quad * 8]);
        }
#pragma unroll
        for (int i = 0; i < 4; i++)
#pragma unroll
            for (int j = 0; j < 4; j++)
                acc[i][j] = __builtin_amdgcn_mfma_f32_16x16x32_f16(af[i], bf[j], acc[i][j], 0, 0, 0);
        __syncthreads();
    }
    // epilogue: D row = quad*4+r, col = r16
#pragma unroll
    for (int i = 0; i < 4; i++)
#pragma unroll
        for (int j = 0; j < 4; j++)
#pragma unroll
            for (int r = 0; r < 4; r++) {
                int rg = m0 + wm * 64 + i * 16 + quad * 4 + r;
                int cg = n0 + wn * 64 + j * 16 + r16;
                float v = acc[i][j][r];
                if (OUT_F16) ((_Float16*)Cv)[(size_t)rg * Ndim + cg] = (_Float16)v;
                else         ((float*)Cv)[(size_t)rg * Ndim + cg] = v;
            }
}

// ========== b/a projections (N=32 each) + beta/g activation, one row/block ==========
__global__ __launch_bounds__(256) void k_ba(const float* __restrict__ hidden,
                                            const float* __restrict__ Wb,
                                            const float* __restrict__ Wa,
                                            const float* __restrict__ dt_bias,
                                            const float* __restrict__ A_log,
                                            float* __restrict__ gout,
                                            float* __restrict__ betaout) {
    int row = blockIdx.x;
    __shared__ float xs[2048];
    __shared__ float part[4][64];
    int t = threadIdx.x;
    for (int c = t; c < 512; c += 256)
        *(f32x4*)&xs[c * 4] = *(const f32x4*)&hidden[(size_t)row * 2048 + c * 4];
    __syncthreads();
    int col = t & 63, kq = t >> 6;
    const float* W = (col < 32) ? Wb : Wa;
    int cc = col & 31;
    float p = 0.f;
#pragma unroll 4
    for (int k = kq * 512; k < kq * 512 + 512; k++)
        p += xs[k] * W[(size_t)k * 32 + cc];
    part[kq][col] = p;
    __syncthreads();
    if (t < 64) {
        float v = part[0][t] + part[1][t] + part[2][t] + part[3][t];
        if (t < 32) {
            betaout[(size_t)row * 32 + t] = 1.f / (1.f + __expf(-v));
        } else {
            int hh = t - 32;
            float x = v + dt_bias[hh];
            float sp = (x > 20.f) ? x : log1pf(__expf(x));
            gout[(size_t)row * 32 + hh] = -__expf(A_log[hh]) * sp;
        }
    }
}

// ===== causal depthwise conv (K=4) + SiLU + split + l2norm(q,k), one row/block =====
__global__ __launch_bounds__(256) void k_conv(const _Float16* __restrict__ mixed,
                                              const float* __restrict__ conv_w,
                                              _Float16* __restrict__ qout,
                                              _Float16* __restrict__ kout,
                                              _Float16* __restrict__ vout) {
    int row = blockIdx.x;
    int l = row & (LL_ - 1);
    __shared__ float yv[CONVD_];
    __shared__ float red[256];
    __shared__ float rinvs[32];
    int t = threadIdx.x;
    for (int c = t; c < CONVD_; c += 256) {
        float acc = 0.f;
#pragma unroll
        for (int j = 0; j < 4; j++) {
            int sl = l - 3 + j;          // per-sequence causal pad
            if (sl >= 0) acc += (float)mixed[(size_t)(row - 3 + j) * CONVD_ + c] * conv_w[c * 4 + j];
        }
        yv[c] = acc / (1.f + __expf(-acc));            // SiLU
    }
    __syncthreads();
    int seg = t >> 3, j8 = t & 7;
    int base = (seg < 16) ? seg * 128 : 2048 + (seg - 16) * 128;
    float ss = 0.f;
#pragma unroll
    for (int i = 0; i < 16; i++) { float vv = yv[base + j8 * 16 + i]; ss += vv * vv; }
    red[t] = ss;
    __syncthreads();
    if (t < 32) {
        float tot = 0.f;
#pragma unroll
        for (int jj = 0; jj < 8; jj++) tot += red[t * 8 + jj];
        rinvs[t] = rsqrtf(tot + 1e-6f);
    }
    __syncthreads();
    for (int c = t; c < CONVD_; c += 256) {
        float y = yv[c];
        if (c < 2048) {
            qout[(size_t)row * 2048 + c] = (_Float16)(y * rinvs[c >> 7] * 0.08838834764831843f);
        } else if (c < 4096) {
            int c2 = c - 2048;
            kout[(size_t)row * 2048 + c2] = (_Float16)(y * rinvs[16 + (c2 >> 7)]);
        } else {
            vout[(size_t)row * 4096 + (c - 4096)] = y;
        }
    }
}

// ===================== gated delta-rule scan =====================
// One wave per (b, h, 4-dv tile): lane = (dvo = l&3, dkg = l>>2 of 16 groups x 8 dk).
// 2048 waves = 8/CU. Decay folded into dot: kv = eg*(k . S_old). 4-deep prefetch,
// raw f16 buffers (cvt deferred to compute). XCD swizzle: all 32 dv-waves of one
// (b,h) land on one XCD (bid%8 == bh%8) for L2 reuse of q/k rows.
__global__ __launch_bounds__(64) void k_scan(const _Float16* __restrict__ q,
                                             const _Float16* __restrict__ k,
                                             const _Float16* __restrict__ v,
                                             const float* __restrict__ g,
                                             const float* __restrict__ beta,
                                             _Float16* __restrict__ o) {
    int bid = blockIdx.x;            // 2048 = 8 slots * 32 dt * 8 xcd
    int xcd  = bid & 7;
    int dt   = (bid >> 3) & 31;
    int slot = bid >> 8;
    int bh = slot * 8 + xcd;         // 0..63
    int b = bh >> 5, h = bh & 31;
    int l = threadIdx.x;
    int dvo = l & 3, dkg = l >> 2;
    int dv = dt * 4 + dvo;
    int hk = h >> 1;                 // GQA repeat_interleave

    float s[8];
#pragma unroll
    for (int i = 0; i < 8; i++) s[i] = 0.f;

    const _Float16* kb_  = k + ((size_t)(b * LL_) * 16 + hk) * 128 + dkg * 8;
    const _Float16* qb_  = q + ((size_t)(b * LL_) * 16 + hk) * 128 + dkg * 8;
    const _Float16* vb_  = v + ((size_t)(b * LL_) * 32 + h) * 128 + dv;
    const float*    gb_  = g + (size_t)(b * LL_) * 32 + h;
    const float*    bb2_ = beta + (size_t)(b * LL_) * 32 + h;
    _Float16*       ob_  = o + ((size_t)(b * LL_) * 32 + h) * 128 + dv;

    half8v kh[4], qh[4];
    float vh[4], gv4[4], bv4[4];

#define LD(T, J)                                                          \
    do {                                                                  \
        kh[J] = *(const half8v*)(kb_ + (size_t)(T) * 2048);               \
        qh[J] = *(const half8v*)(qb_ + (size_t)(T) * 2048);               \
        vh[J] = (float)vb_[(size_t)(T) * 4096];                           \
        gv4[J] = gb_[(size_t)(T) * 32];                                   \
        bv4[J] = bb2_[(size_t)(T) * 32];                                  \
    } while (0)

#define CP(T, J)                                                          \
    do {                                                                  \
        float kf[8], qf[8];                                               \
        _Pragma("unroll")                                                 \
        for (int jj = 0; jj < 8; jj++) {                                  \
            kf[jj] = (float)kh[J][jj];                                    \
            qf[jj] = (float)qh[J][jj];                                    \
        }                                                                 \
        float eg_ = __expf(gv4[J]);                                       \
        float p0_ = 0.f, p1_ = 0.f;                                       \
        _Pragma("unroll")                                                 \
        for (int jj = 0; jj < 4; jj++) {                                  \
            p0_ += kf[jj] * s[jj];                                        \
            p1_ += kf[4 + jj] * s[4 + jj];                                \
        }                                                                 \
        float kv_ = (p0_ + p1_) * eg_;                                    \
        kv_ += __shfl_xor(kv_, 4);                                        \
        kv_ += __shfl_xor(kv_, 8);                                        \
        kv_ += __shfl_xor(kv_, 16);                                       \
        kv_ += __shfl_xor(kv_, 32);                                       \
        float dlt_ = (vh[J] - kv_) * bv4[J];                              \
        _Pragma("unroll")                                                 \
        for (int jj = 0; jj < 8; jj++)                                    \
            s[jj] = fmaf(s[jj], eg_, kf[jj] * dlt_);                      \
        float o0_ = 0.f, o1_ = 0.f;                                       \
        _Pragma("unroll")                                                 \
        for (int jj = 0; jj < 4; jj++) {                                  \
            o0_ += qf[jj] * s[jj];                                        \
            o1_ += qf[4 + jj] * s[4 + jj];                                \
        }                                                                 \
        float ov_ = o0_ + o1_;                                            \
        ov_ += __shfl_xor(ov_, 4);                                        \
        ov_ += __shfl_xor(ov_, 8);                                        \
        ov_ += __shfl_xor(ov_, 16);                                       \
        ov_ += __shfl_xor(ov_, 32);                                       \
        if (l < 4) ob_[(size_t)(T) * 4096] = (_Float16)ov_;               \
    } while (0)

    LD(0, 0); LD(1, 1); LD(2, 2); LD(3, 3);
    for (int t = 0; t + 4 < LL_; t += 4) {
        CP(t, 0);     LD(t + 4, 0);
        CP(t + 1, 1); LD(t + 5, 1);
        CP(t + 2, 2); LD(t + 6, 2);
        CP(t + 3, 3); LD(t + 7, 3);
    }
    CP(LL_ - 4, 0); CP(LL_ - 3, 1); CP(LL_ - 2, 2); CP(LL_ - 1, 3);
#undef LD
#undef CP
}

// ===================== gated RMSNorm, one row/block, f16 in/out =====================
__global__ __launch_bounds__(256) void k_rmsnorm(const _Float16* __restrict__ o,
                                                 const _Float16* __restrict__ z,
                                                 const float* __restrict__ norm_w,
                                                 _Float16* __restrict__ gn) {
    int row = blockIdx.x;
    __shared__ float gv[4096];
    __shared__ float red[256];
    __shared__ float rinv[32];
    int t = threadIdx.x;
    int h = t >> 3, j = t & 7;
    size_t base = (size_t)row * 4096 + h * 128 + j * 16;
    float ss = 0.f;
#pragma unroll
    for (int i = 0; i < 16; i++) {
        float ov = (float)o[base + i];
        float zv = (float)z[base + i];
        float gg = ov * zv / (1.f + __expf(-zv));
        gv[h * 128 + j * 16 + i] = gg;
        ss += gg * gg;
    }
    red[t] = ss;
    __syncthreads();
    if (t < 32) {
        float tot = 0.f;
#pragma unroll
        for (int jj = 0; jj < 8; jj++) tot += red[t * 8 + jj];
        rinv[t] = rsqrtf(tot * (1.f / 128.f) + 1e-6f);
    }
    __syncthreads();
#pragma unroll
    for (int i = 0; i < 16; i++) {
        int idx = h * 128 + j * 16 + i;
        gn[(size_t)row * 4096 + idx] = (_Float16)(gv[idx] * rinv[h] * norm_w[idx & 127]);
    }
}

// ===================== launch =====================
// Workspace layout (145 MB span; all aliases stream-ordered write-after-last-read):
//   [  0, 16) XH    -> GN [0,32)
//   [ 16, 48) WQKVT -> QB [16,32) + KB [32,48)
//   [ 48,112) MIXED -> OB [48,80), WZT [80,96)
//   [ 96,128) ZH
//   [112,144) VB    -> WOUTT [128,144)
//   [144,145) GB + BBUF
extern "C" void kernel_launch(void* const* d_in, const int* in_sizes, int n_in,
                              void* d_out, int out_size, void* d_ws, size_t ws_size,
                              hipStream_t stream) {
    const float* hidden  = (const float*)d_in[0];
    const float* W_qkv   = (const float*)d_in[1];
    const float* W_z     = (const float*)d_in[2];
    const float* W_b     = (const float*)d_in[3];
    const float* W_a     = (const float*)d_in[4];
    const float* conv_w  = (const float*)d_in[5];
    const float* dt_bias = (const float*)d_in[6];
    const float* A_log   = (const float*)d_in[7];
    const float* norm_w  = (const float*)d_in[8];
    const float* W_out   = (const float*)d_in[9];
    float* out = (float*)d_out;

    const size_t MB = 1ull << 20;
    char* ws = (char*)d_ws;
    if (ws_size < 146 * MB) {
        hipMemsetAsync(d_out, 0, (size_t)out_size * sizeof(float), stream);
        return;
    }

    _Float16* XH    = (_Float16*)(ws + 0 * MB);
    _Float16* WQKVT = (_Float16*)(ws + 16 * MB);
    _Float16* MIXED = (_Float16*)(ws + 48 * MB);
    _Float16* QB    = (_Float16*)(ws + 16 * MB);
    _Float16* KB    = (_Float16*)(ws + 32 * MB);
    _Float16* VB    = (_Float16*)(ws + 112 * MB);
    _Float16* OB    = (_Float16*)(ws + 48 * MB);
    _Float16* WZT   = (_Float16*)(ws + 80 * MB);
    _Float16* ZH    = (_Float16*)(ws + 96 * MB);
    _Float16* GN    = (_Float16*)(ws + 0 * MB);
    _Float16* WOUTT = (_Float16*)(ws + 128 * MB);
    float*    GB    = (float*)(ws + 144 * MB);
    float*    BBUF  = (float*)(ws + 144 * MB + 512 * 1024);

    k_convert<<<(MM_ * DD_ / 4 + 255) / 256, 256, 0, stream>>>(hidden, XH, MM_ * DD_ / 4);
    k_transpose<<<dim3(CONVD_ / 32, DD_ / 32), 256, 0, stream>>>(W_qkv, WQKVT, DD_, CONVD_);
    k_gemm<true><<<dim3(CONVD_ / 128, MM_ / 128), 256, 0, stream>>>(XH, WQKVT, MIXED, MM_, CONVD_, DD_);
    k_ba<<<MM_, 256, 0, stream>>>(hidden, W_b, W_a, dt_bias, A_log, GB, BBUF);
    k_conv<<<MM_, 256, 0, stream>>>(MIXED, conv_w, QB, KB, VB);
    k_scan<<<2048, 64, 0, stream>>>(QB, KB, VB, GB, BBUF, OB);
    k_transpose<<<dim3(VALD_ / 32, DD_ / 32), 256, 0, stream>>>(W_z, WZT, DD_, VALD_);
    k_gemm<true><<<dim3(VALD_ / 128, MM_ / 128), 256, 0, stream>>>(XH, WZT, ZH, MM_, VALD_, DD_);
    k_rmsnorm<<<MM_, 256, 0, stream>>>(OB, ZH, norm_w, GN);
    k_transpose<<<dim3(DD_ / 32, VALD_ / 32), 256, 0, stream>>>(W_out, WOUTT, VALD_, DD_);
    k_gemm<false><<<dim3(DD_ / 128, MM_ / 128), 256, 0, stream>>>(GN, WOUTT, out, MM_, DD_, VALD_);
}